// Round 1
// baseline (19791.356 us; speedup 1.0000x reference)
//
#include <hip/hip_runtime.h>
#include <math.h>

typedef _Float16 f16;
typedef f16 f16x2 __attribute__((ext_vector_type(2)));
typedef f16 f16x4 __attribute__((ext_vector_type(4)));
typedef f16 f16x8 __attribute__((ext_vector_type(8)));
typedef float f32x4 __attribute__((ext_vector_type(4)));

#define NB 128      // batch
#define TT 256      // time steps
#define DD 1024     // input dim
#define HH 1024     // hidden dim
#define PP 196      // spatial positions (14*14)
#define K3 3072     // folded K = D + H + H
#define FOURH 4096

// ---------------- P1: h0 = c0 = mean_p A[n][h][:]  ----------------
__global__ void k_h0(const float* __restrict__ A, float* __restrict__ c_state,
                     f16* __restrict__ act_h0) {
  int idx = blockIdx.x * 256 + threadIdx.x;            // (n*1024 + h), 131072 total
  const float4* ap = (const float4*)(A + (size_t)idx * PP);
  float s = 0.f;
#pragma unroll
  for (int i = 0; i < PP / 4; ++i) { float4 v = ap[i]; s += v.x + v.y + v.z + v.w; }
  float m = s * (1.0f / PP);
  c_state[idx] = m;
  act_h0[idx] = (f16)m;
}

// ---------------- P2: A[n][h][p] fp32 -> A2[n][p][h] fp16 (tiled transpose) ---
__global__ void k_At(const float* __restrict__ A, f16* __restrict__ A2) {
  __shared__ float tile[32][33];
  int p0 = blockIdx.x * 32, h0 = blockIdx.y * 32, n = blockIdx.z;
  for (int i = threadIdx.x; i < 1024; i += 256) {
    int r = i >> 5, c = i & 31;                        // r: h-local, c: p-local
    int p = p0 + c;
    float v = 0.f;
    if (p < PP) v = A[((size_t)n * HH + h0 + r) * PP + p];
    tile[r][c] = v;
  }
  __syncthreads();
  for (int i = threadIdx.x; i < 1024; i += 256) {
    int r = i >> 5, c = i & 31;                        // r: p-local, c: h-local
    int p = p0 + r;
    if (p < PP) A2[((size_t)n * PP + p) * HH + h0 + c] = (f16)tile[c][r];
  }
}

// ------ P3: Wt[j][k] fp16, j in [0,4096) cols, k in [0,3072) = [Wx;Wh;Wattn] --
__global__ void k_Wt(const float* __restrict__ Wx, const float* __restrict__ Wh,
                     const float* __restrict__ Wa, f16* __restrict__ Wt) {
  __shared__ float tile[32][33];
  int k0 = blockIdx.x * 32, j0 = blockIdx.y * 32;
  const float* src; int kb;
  if (k0 < 1024)      { src = Wx; kb = k0; }
  else if (k0 < 2048) { src = Wh; kb = k0 - 1024; }
  else                { src = Wa; kb = k0 - 2048; }
  for (int i = threadIdx.x; i < 1024; i += 256) {
    int r = i >> 5, c = i & 31;
    tile[r][c] = src[(size_t)(kb + r) * FOURH + j0 + c];
  }
  __syncthreads();
  for (int i = threadIdx.x; i < 1024; i += 256) {
    int r = i >> 5, c = i & 31;                        // r: j-local, c: k-local
    Wt[(size_t)(j0 + r) * K3 + k0 + c] = (f16)tile[c][r];
  }
}

// ---------------- P4: x fp32 -> fp16 ----------------
__global__ void k_xcvt(const float* __restrict__ x, f16* __restrict__ xh) {
  size_t i = (size_t)blockIdx.x * 256 + threadIdx.x;   // one float4 per thread
  float4 v = ((const float4*)x)[i];
  f16x4 o; o[0] = (f16)v.x; o[1] = (f16)v.y; o[2] = (f16)v.z; o[3] = (f16)v.w;
  *(f16x4*)(xh + i * 4) = o;
}

// ---------------- per-step: scores[n][p] = (h . A2[n][p][:]) / 32 -------------
__global__ __launch_bounds__(512) void k_scores(const f16* __restrict__ A2,
                                                const f16* __restrict__ acth,
                                                float* __restrict__ scores) {
  int n = blockIdx.x >> 1, ph = (blockIdx.x & 1) * 98;
  int lane = threadIdx.x & 63, wid = threadIdx.x >> 6;
  const f16x8* hp = (const f16x8*)(acth + (size_t)n * HH + lane * 16);
  f16x8 hv0 = hp[0], hv1 = hp[1];
  float hf[16];
#pragma unroll
  for (int e = 0; e < 8; ++e) { hf[e] = (float)hv0[e]; hf[8 + e] = (float)hv1[e]; }
  const f16* An = A2 + (size_t)n * PP * HH;
#pragma unroll 2
  for (int p = ph + wid; p < ph + 98; p += 8) {
    const f16x8* apv = (const f16x8*)(An + (size_t)p * HH + lane * 16);
    f16x8 a0 = apv[0], a1 = apv[1];
    float acc = 0.f;
#pragma unroll
    for (int e = 0; e < 8; ++e)
      acc += hf[e] * (float)a0[e] + hf[8 + e] * (float)a1[e];
#pragma unroll
    for (int off = 32; off > 0; off >>= 1) acc += __shfl_xor(acc, off, 64);
    if (lane == 0) scores[n * PP + p] = acc * 0.03125f;
  }
}

// -------- per-step: softmax over p, attn[n][h] = sum_p w[p] A2[n][p][h] -------
__global__ __launch_bounds__(256) void k_attn(const f16* __restrict__ A2,
                                              const float* __restrict__ scores,
                                              f16* __restrict__ attnb) {
  __shared__ float sm[256];
  __shared__ float wexp[PP];
  int n = blockIdx.x >> 1, hh0 = (blockIdx.x & 1) * 512;
  int tid = threadIdx.x;
  float s = (tid < PP) ? scores[n * PP + tid] : -1e30f;
  sm[tid] = s;
  __syncthreads();
  for (int st = 128; st > 0; st >>= 1) {
    if (tid < st) sm[tid] = fmaxf(sm[tid], sm[tid + st]);
    __syncthreads();
  }
  float mx = sm[0];
  __syncthreads();
  float e = (tid < PP) ? __expf(s - mx) : 0.f;
  if (tid < PP) wexp[tid] = e;
  sm[tid] = e;
  __syncthreads();
  for (int st = 128; st > 0; st >>= 1) {
    if (tid < st) sm[tid] += sm[tid + st];
    __syncthreads();
  }
  float rinv = 1.0f / sm[0];
  const f16x2* Ap = (const f16x2*)(A2 + (size_t)n * PP * HH + hh0);
  float ax = 0.f, ay = 0.f;
#pragma unroll 4
  for (int p = 0; p < PP; ++p) {
    f16x2 v = Ap[(size_t)p * (HH / 2) + tid];
    float w = wexp[p];
    ax += w * (float)v[0];
    ay += w * (float)v[1];
  }
  f16x2 o; o[0] = (f16)(ax * rinv); o[1] = (f16)(ay * rinv);
  *(f16x2*)(attnb + (size_t)n * HH + hh0 + tid * 2) = o;
}

// ---- per-step: a = [x_t|h|attn] @ Wt^T + b ; gates ; c,h update ; write out --
// 128 blocks x 256 thr (4 waves). Block covers all 128 rows x 32 cols
// (cols = 4 gates x 8 h's, h-slice hs..hs+7). Wave w: mhalf=w&1 (64 rows),
// khalf=w>>1 (1536 of K=3072). Register tile per wave: 4 m-tiles x 2 n-tiles,
// operands streamed straight from L2 (16B/lane frag loads use full 64B lines).
__global__ __launch_bounds__(256, 1) void k_gemm(
    const f16* __restrict__ xh, const f16* __restrict__ acth,
    const f16* __restrict__ attnb, const f16* __restrict__ Wt,
    const float* __restrict__ bias, float* __restrict__ c_state,
    f16* __restrict__ acth_next, float* __restrict__ out, int t) {
  __shared__ float a_s[128 * 33];
  int tid = threadIdx.x;
  int lane = tid & 63, w = tid >> 6;
  int mhalf = w & 1, khalf = w >> 1;
  int l15 = lane & 15, quad = lane >> 4;
  int hs = blockIdx.x * 8;

  // global weight columns for the two n-tiles: c = nt*16+l15, j = (c>>3)*1024+hs+(c&7)
  int c0 = l15, c1 = 16 + l15;
  size_t j0 = (size_t)((c0 >> 3) * 1024 + hs + (c0 & 7));
  size_t j1 = (size_t)((c1 >> 3) * 1024 + hs + (c1 & 7));
  const f16* W0 = Wt + j0 * K3 + quad * 8;
  const f16* W1 = Wt + j1 * K3 + quad * 8;

  f32x4 acc[4][2];
#pragma unroll
  for (int i = 0; i < 4; ++i)
#pragma unroll
    for (int j = 0; j < 2; ++j)
#pragma unroll
      for (int e = 0; e < 4; ++e) acc[i][j][e] = 0.f;

  int rowbase = mhalf * 64 + l15;

  auto seg = [&](const f16* base, size_t rstride, int gk0, int nks) {
#pragma unroll 4
    for (int ks = 0; ks < nks; ++ks) {
      int gk = gk0 + ks * 32;
      const f16* ap = base + ks * 32 + quad * 8;
      f16x8 b0 = *(const f16x8*)(W0 + gk);
      f16x8 b1 = *(const f16x8*)(W1 + gk);
      f16x8 a0 = *(const f16x8*)(ap + (size_t)(rowbase)      * rstride);
      f16x8 a1 = *(const f16x8*)(ap + (size_t)(rowbase + 16) * rstride);
      f16x8 a2 = *(const f16x8*)(ap + (size_t)(rowbase + 32) * rstride);
      f16x8 a3 = *(const f16x8*)(ap + (size_t)(rowbase + 48) * rstride);
      acc[0][0] = __builtin_amdgcn_mfma_f32_16x16x32_f16(a0, b0, acc[0][0], 0, 0, 0);
      acc[0][1] = __builtin_amdgcn_mfma_f32_16x16x32_f16(a0, b1, acc[0][1], 0, 0, 0);
      acc[1][0] = __builtin_amdgcn_mfma_f32_16x16x32_f16(a1, b0, acc[1][0], 0, 0, 0);
      acc[1][1] = __builtin_amdgcn_mfma_f32_16x16x32_f16(a1, b1, acc[1][1], 0, 0, 0);
      acc[2][0] = __builtin_amdgcn_mfma_f32_16x16x32_f16(a2, b0, acc[2][0], 0, 0, 0);
      acc[2][1] = __builtin_amdgcn_mfma_f32_16x16x32_f16(a2, b1, acc[2][1], 0, 0, 0);
      acc[3][0] = __builtin_amdgcn_mfma_f32_16x16x32_f16(a3, b0, acc[3][0], 0, 0, 0);
      acc[3][1] = __builtin_amdgcn_mfma_f32_16x16x32_f16(a3, b1, acc[3][1], 0, 0, 0);
    }
  };

  if (khalf == 0) {
    seg(xh + (size_t)t * DD, (size_t)TT * DD, 0, 32);    // x part, k 0..1023
    seg(acth, DD, 1024, 16);                             // h part, k 1024..1535
  } else {
    seg(acth + 512, DD, 1536, 16);                       // h part, k 1536..2047
    seg(attnb, DD, 2048, 32);                            // attn part, k 2048..3071
  }

  // combine k-halves through LDS: khalf0 writes, khalf1 adds
  if (khalf == 0) {
#pragma unroll
    for (int mt = 0; mt < 4; ++mt)
#pragma unroll
      for (int nt = 0; nt < 2; ++nt)
#pragma unroll
        for (int jr = 0; jr < 4; ++jr)
          a_s[(mhalf * 64 + mt * 16 + quad * 4 + jr) * 33 + nt * 16 + l15] =
              acc[mt][nt][jr];
  }
  __syncthreads();
  if (khalf == 1) {
#pragma unroll
    for (int mt = 0; mt < 4; ++mt)
#pragma unroll
      for (int nt = 0; nt < 2; ++nt)
#pragma unroll
        for (int jr = 0; jr < 4; ++jr)
          a_s[(mhalf * 64 + mt * 16 + quad * 4 + jr) * 33 + nt * 16 + l15] +=
              acc[mt][nt][jr];
  }
  __syncthreads();

  // gates + LSTM update + outputs
  for (int idx = tid; idx < 1024; idx += 256) {
    int n = idx >> 3, hh = idx & 7;
    float ai = a_s[n * 33 + hh]       + bias[hs + hh];
    float af = a_s[n * 33 + 8 + hh]   + bias[1024 + hs + hh];
    float ao = a_s[n * 33 + 16 + hh]  + bias[2048 + hs + hh];
    float ag = a_s[n * 33 + 24 + hh]  + bias[3072 + hs + hh];
    float ig = 1.f / (1.f + __expf(-ai));
    float fg = 1.f / (1.f + __expf(-af));
    float og = 1.f / (1.f + __expf(-ao));
    float gg = tanhf(ag);
    int ch = n * HH + hs + hh;
    float cn = fg * c_state[ch] + ig * gg;
    c_state[ch] = cn;
    float hn = og * tanhf(cn);
    out[((size_t)n * TT + t) * HH + hs + hh] = hn;
    acth_next[ch] = (f16)hn;
  }
}

extern "C" void kernel_launch(void* const* d_in, const int* in_sizes, int n_in,
                              void* d_out, int out_size, void* d_ws, size_t ws_size,
                              hipStream_t stream) {
  const float* x  = (const float*)d_in[0];
  const float* A  = (const float*)d_in[1];
  const float* Wx = (const float*)d_in[2];
  const float* Wh = (const float*)d_in[3];
  const float* Wa = (const float*)d_in[4];
  const float* b  = (const float*)d_in[5];
  float* out = (float*)d_out;

  char* ws = (char*)d_ws;
  f16* A2 = (f16*)ws;        ws += (size_t)NB * PP * HH * 2;   // 51.4 MB
  f16* Wt = (f16*)ws;        ws += (size_t)FOURH * K3 * 2;     // 25.2 MB
  f16* xh = (f16*)ws;        ws += (size_t)NB * TT * DD * 2;   // 67.1 MB
  f16* acth0 = (f16*)ws;     ws += (size_t)NB * HH * 2;
  f16* acth1 = (f16*)ws;     ws += (size_t)NB * HH * 2;
  f16* attnb = (f16*)ws;     ws += (size_t)NB * HH * 2;
  float* c_state = (float*)ws; ws += (size_t)NB * HH * 4;
  float* scores = (float*)ws;  ws += (size_t)NB * PP * 4;
  f16* acth[2] = { acth0, acth1 };

  k_h0<<<512, 256, 0, stream>>>(A, c_state, acth0);
  k_At<<<dim3(7, 32, NB), 256, 0, stream>>>(A, A2);
  k_Wt<<<dim3(96, 128), 256, 0, stream>>>(Wx, Wh, Wa, Wt);
  k_xcvt<<<32768, 256, 0, stream>>>(x, xh);

  for (int t = 0; t < TT; ++t) {
    k_scores<<<256, 512, 0, stream>>>(A2, acth[t & 1], scores);
    k_attn<<<256, 256, 0, stream>>>(A2, scores, attnb);
    k_gemm<<<128, 256, 0, stream>>>(xh, acth[t & 1], attnb, Wt, b, c_state,
                                    acth[(t + 1) & 1], out, t);
  }
}